// Round 9
// baseline (72.669 us; speedup 1.0000x reference)
//
#include <hip/hip_runtime.h>
#include <hip/hip_bf16.h>

#define NF 16
#define NH 32
#define LOG2E  1.44269504088896340736f
#define TILE 32
#define OSTG 33                   // out-stage row stride (floats): conflict-free

typedef short bf16x8 __attribute__((ext_vector_type(8)));
typedef float f32x16 __attribute__((ext_vector_type(16)));
typedef float f32x4  __attribute__((ext_vector_type(4)));

#if __has_builtin(__builtin_amdgcn_exp2f)
#define EXP2(x) __builtin_amdgcn_exp2f(x)
#else
#define EXP2(x) exp2f(x)
#endif

__device__ __forceinline__ short f2bf(float f) {
    __hip_bfloat16 b = __float2bfloat16(f);  // RNE
    return *reinterpret_cast<short*>(&b);
}

__device__ __forceinline__ bf16x8 cvt8(float4 a, float4 b) {
    bf16x8 r;
    r[0] = f2bf(a.x); r[1] = f2bf(a.y); r[2] = f2bf(a.z); r[3] = f2bf(a.w);
    r[4] = f2bf(b.x); r[5] = f2bf(b.y); r[6] = f2bf(b.z); r[7] = f2bf(b.w);
    return r;
}

__device__ __forceinline__ float sig2(float v) {   // arg pre-scaled by log2e
    return __builtin_amdgcn_rcpf(1.0f + EXP2(-v));
}
__device__ __forceinline__ float tanh2(float v) {  // arg pre-scaled by 2*log2e
    return 1.0f - 2.0f * __builtin_amdgcn_rcpf(1.0f + EXP2(v));
}

// non-temporal 16B store (clang ext_vector type required by the builtin)
__device__ __forceinline__ void nt_store4(float* p, float4 v) {
    f32x4 w = { v.x, v.y, v.z, v.w };
    __builtin_nontemporal_store(w, (f32x4*)p);
}

// ---------------------------------------------------------------------------
// Prep: pack W' = [Wx; Wh; bias; pad] (64x32 per gate, pre-scaled by log2e,
// gate 2 by 2*log2e) into MFMA A-operand fragments. wcs = scaled peephole.
// Wpack index: (((g*4)+ks)*64 + l)*8 + e  -> 8192 shorts = 16 KB.
// ---------------------------------------------------------------------------
__global__ void prep_kernel(const float* __restrict__ Wx, const float* __restrict__ Wh,
                            const float* __restrict__ bx, const float* __restrict__ bh,
                            const float* __restrict__ bg, const float* __restrict__ wc,
                            short* __restrict__ Wpack, float* __restrict__ wcs)
{
    int t = blockIdx.x * blockDim.x + threadIdx.x;
    if (t < 4 * 4 * 64) {
        int g  = t >> 8;
        int ks = (t >> 6) & 3;
        int l  = t & 63;
        int col  = l & 31;
        int half = l >> 5;
        float scale = (g == 2) ? 2.0f * LOG2E : LOG2E;
        #pragma unroll
        for (int e = 0; e < 8; ++e) {
            int gk = ks * 16 + half * 8 + e;
            float w;
            if (gk < NF)            w = Wx[(g * NF + gk) * NH + col];
            else if (gk < NF + NH)  w = Wh[(g * NH + (gk - NF)) * NH + col];
            else if (gk == 48)      w = bx[g * NH + col] + bh[g * NH + col] + bg[g * NH + col];
            else                    w = 0.0f;
            Wpack[t * 8 + e] = f2bf(w * scale);
        }
    }
    if (t < 3 * NH) wcs[t] = wc[t] * LOG2E;
}

// per-tile input loads, straight to registers (lane owns node nb+col).
// B-fragment is row-contiguous per node, so per-lane float4s are natural.
#define LOAD_TILE(xv, hv, cv, t_) {                                          \
    const long nb_ = (long)(t_) * TILE;                                      \
    const float* px = x   + (nb_ + col) * NF + half * 8;                     \
    xv[0] = *(const float4*)px;        xv[1] = *(const float4*)(px + 4);     \
    const float* ph = hin + (nb_ + col) * NH + half * 8;                     \
    hv[0] = *(const float4*)ph;        hv[1] = *(const float4*)(ph + 4);     \
    hv[2] = *(const float4*)(ph + 16); hv[3] = *(const float4*)(ph + 20);    \
    const float* pc = cin + (nb_ + col) * NH + 4 * half;                     \
    cv[0] = *(const float4*)pc;        cv[1] = *(const float4*)(pc + 8);     \
    cv[2] = *(const float4*)(pc + 16); cv[3] = *(const float4*)(pc + 24);    \
    asm volatile("" ::: "memory"); /* keep issue point; wait only at use */  }

// ---------------------------------------------------------------------------
// Consume one tile. Swapped-operand MFMA: D[row=j][col=node]; lane owns node
// nb+(lane&31). Weights come from block-shared LDS (conflict-free b128).
// Outputs transpose through per-wave stride-33 LDS, NT-stored as 1KB rows.
// ---------------------------------------------------------------------------
__device__ __forceinline__ void do_tile(
    const bf16x8* __restrict__ wlds, float* hs, float* cs, long nb,
    const float4* xv, const float4* hv, const float4* cv, bf16x8 a3,
    const float* __restrict__ wcs, const float* __restrict__ Wlin, float bl,
    float* __restrict__ out, float* __restrict__ h0o, float* __restrict__ co,
    int lane)
{
    const int col  = lane & 31;
    const int half = lane >> 5;

    bf16x8 a0 = cvt8(xv[0], xv[1]);
    bf16x8 a1 = cvt8(hv[0], hv[1]);
    bf16x8 a2 = cvt8(hv[2], hv[3]);

    // ---- 16 MFMAs: 4 gates x K=64 (bias folded); A-frags re-read from LDS ----
    f32x16 acc[4];
    #pragma unroll
    for (int g = 0; g < 4; ++g) {
        #pragma unroll
        for (int r = 0; r < 16; ++r) acc[g][r] = 0.0f;
        bf16x8 w0 = wlds[(g * 4 + 0) * 64 + lane];
        bf16x8 w1 = wlds[(g * 4 + 1) * 64 + lane];
        bf16x8 w2 = wlds[(g * 4 + 2) * 64 + lane];
        bf16x8 w3 = wlds[(g * 4 + 3) * 64 + lane];
        acc[g] = __builtin_amdgcn_mfma_f32_32x32x16_bf16(w0, a0, acc[g], 0, 0, 0);
        acc[g] = __builtin_amdgcn_mfma_f32_32x32x16_bf16(w1, a1, acc[g], 0, 0, 0);
        acc[g] = __builtin_amdgcn_mfma_f32_32x32x16_bf16(w2, a2, acc[g], 0, 0, 0);
        acc[g] = __builtin_amdgcn_mfma_f32_32x32x16_bf16(w3, a3, acc[g], 0, 0, 0);
    }

    // ---- epilogue: gates -> h/c into per-wave out-stage LDS ----
    float outacc = 0.0f;
    const float c2l = 2.0f * LOG2E;
    #pragma unroll
    for (int jg = 0; jg < 4; ++jg) {
        const int jbase = jg * 8 + 4 * half;
        const float4 w0 = *(const float4*)(wcs + 0 * NH + jbase);
        const float4 w1 = *(const float4*)(wcs + 1 * NH + jbase);
        const float4 w2 = *(const float4*)(wcs + 2 * NH + jbase);
        const float4 wl = *(const float4*)(Wlin + jbase);
        float h4[4], c4[4];
        #pragma unroll
        for (int q = 0; q < 4; ++q) {
            const int r = jg * 4 + q;
            const float ci = ((const float*)&cv[jg])[q];
            const float ig = sig2(fmaf(((const float*)&w0)[q], ci, acc[0][r]));
            const float fg = sig2(fmaf(((const float*)&w1)[q], ci, acc[1][r]));
            const float tg = tanh2(acc[2][r]);
            const float cn = fg * ci + ig * tg;
            const float og = sig2(fmaf(((const float*)&w2)[q], cn, acc[3][r]));
            const float hh = og * tanh2(cn * c2l);
            c4[q] = cn;
            h4[q] = hh;
            outacc = fmaf(fmaxf(hh, 0.0f), ((const float*)&wl)[q], outacc);
        }
        *(float4*)&hs[col * OSTG + jbase] = make_float4(h4[0], h4[1], h4[2], h4[3]);
        *(float4*)&cs[col * OSTG + jbase] = make_float4(c4[0], c4[1], c4[2], c4[3]);
    }

    // ---- transpose read + coalesced NT write-back (DS in-order per wave) ----
    float* hrow = h0o + nb * NH;
    float* crow = co  + nb * NH;
    #pragma unroll
    for (int rep = 0; rep < 4; ++rep) {
        const int tt = lane + rep * 64;
        const int nd = tt >> 3, j4 = (tt & 7) * 4;
        float4 vh = *(const float4*)&hs[nd * OSTG + j4];
        float4 vc = *(const float4*)&cs[nd * OSTG + j4];
        nt_store4(hrow + tt * 4, vh);
        nt_store4(crow + tt * 4, vc);
    }

    outacc += __shfl_xor(outacc, 32, 64);
    if (half == 0) __builtin_nontemporal_store(outacc + bl, &out[nb + col]);
}

// ---------------------------------------------------------------------------
// Persistent grid-stride loop, reg-resident input double-buffer (named sets,
// static indexing), weights in block-shared LDS. 3 blocks/CU x 4 waves.
// ---------------------------------------------------------------------------
__global__ __launch_bounds__(256, 3) void lstm_kernel(
    const float* __restrict__ x, const float* __restrict__ hin,
    const float* __restrict__ cin,
    const float* __restrict__ Wlin, const float* __restrict__ blin,
    const short* __restrict__ Wpack, const float* __restrict__ wcs,
    float* __restrict__ out, float* __restrict__ h0o, float* __restrict__ co,
    int ntiles, int wstride)
{
    __shared__ short wlds[4 * 4 * 64 * 8];   // 16 KB, shared by all waves
    __shared__ float hstg[4][32 * OSTG];     // 16.9 KB
    __shared__ float cstg[4][32 * OSTG];     // 16.9 KB  -> 50176 B total

    const int lane = threadIdx.x & 63;
    const int wave = threadIdx.x >> 6;
    const int col  = lane & 31;
    const int half = lane >> 5;
    float* hs = hstg[wave];
    float* cs = cstg[wave];

    // ---- one-time: cooperative weight stage into LDS (1024 x float4) ----
    {
        const float4* src = (const float4*)Wpack;
        float4* dst = (float4*)wlds;
        #pragma unroll
        for (int i = 0; i < 4; ++i)
            dst[threadIdx.x + 256 * i] = src[threadIdx.x + 256 * i];
    }
    __syncthreads();
    const bf16x8* wfr = (const bf16x8*)wlds;

    bf16x8 a3;
    #pragma unroll
    for (int e = 0; e < 8; ++e) a3[e] = 0;
    if (half == 0) a3[0] = (short)0x3F80;    // bf16 1.0 at k=48 (bias input)
    const float bl = blin[0];

    const int S = wstride;
    const int last = ntiles - 1;
    int t = blockIdx.x * 4 + wave;           // 3072 waves <= 15625 tiles

    float4 xA[2], hA[4], cA[4], xB[2], hB[4], cB[4];

    LOAD_TILE(xA, hA, cA, t);
    {   // peeled first iteration: prefetch B, compute A
        int tn = t + S; if (tn > last) tn = last;
        LOAD_TILE(xB, hB, cB, tn);
        do_tile(wfr, hs, cs, (long)t * TILE, xA, hA, cA, a3,
                wcs, Wlin, bl, out, h0o, co, lane);
        t += S;
    }
    if (t < ntiles) {
        for (;;) {
            {   // compute B, prefetch A
                int tn = t + S; if (tn > last) tn = last;
                LOAD_TILE(xA, hA, cA, tn);
                do_tile(wfr, hs, cs, (long)t * TILE, xB, hB, cB, a3,
                        wcs, Wlin, bl, out, h0o, co, lane);
            }
            t += S; if (t >= ntiles) break;
            {   // compute A, prefetch B
                int tn = t + S; if (tn > last) tn = last;
                LOAD_TILE(xB, hB, cB, tn);
                do_tile(wfr, hs, cs, (long)t * TILE, xA, hA, cA, a3,
                        wcs, Wlin, bl, out, h0o, co, lane);
            }
            t += S; if (t >= ntiles) break;
        }
    }
}

extern "C" void kernel_launch(void* const* d_in, const int* in_sizes, int n_in,
                              void* d_out, int out_size, void* d_ws, size_t ws_size,
                              hipStream_t stream) {
    const float* x    = (const float*)d_in[0];
    // d_in[1] = edge_index (unused, K=1 ChebConv), d_in[2] = edge_weight (unused)
    const float* h    = (const float*)d_in[3];
    const float* c    = (const float*)d_in[4];
    const float* Wx   = (const float*)d_in[5];
    const float* bx   = (const float*)d_in[6];
    const float* Wh   = (const float*)d_in[7];
    const float* bh   = (const float*)d_in[8];
    const float* wc   = (const float*)d_in[9];
    const float* bg   = (const float*)d_in[10];
    const float* Wlin = (const float*)d_in[11];
    const float* blin = (const float*)d_in[12];

    const int N = in_sizes[0] / NF;          // 500000
    const int ntiles = N / TILE;             // 15625 (N % 32 == 0)

    float* out = (float*)d_out;              // [N,1]
    float* h0o = out + N;                    // [N,32]
    float* co  = h0o + (size_t)N * NH;       // [N,32]

    short* Wpack = (short*)d_ws;                                   // 16384 B
    float* wcs   = (float*)((char*)d_ws + 4 * 4 * 64 * 8 * sizeof(short));

    prep_kernel<<<4, 256, 0, stream>>>(Wx, Wh, bx, bh, bg, wc, Wpack, wcs);

    const int grid = 768;                    // 3 blocks/CU (LDS- and VGPR-exact)
    const int wstride = grid * 4;            // 3072 waves
    lstm_kernel<<<grid, 256, 0, stream>>>(
        x, h, c, Wlin, blin, Wpack, wcs, out, h0o, co, ntiles, wstride);
}